// Round 10
// baseline (115.698 us; speedup 1.0000x reference)
//
#include <hip/hip_runtime.h>
#include <cstdint>

#define T_STEPS 16384

// ---- workspace float offsets ----
#define WS_U     0        // 256
#define WS_V     256      // 256
#define WS_W1ZT  512      // 2048 [c][k]
#define WS_PEN   2560     // 64
#define WS_A     2624     // 64
#define WS_W4T   2688     // 512 [i][z]
#define WS_UDC   3200     // 128
#define WS_VDC   3328     // 128
#define WS_D3T   3456     // 512 [k][z]
#define WS_W2T   3968     // 32768 [k][j] 256x128
#define WS_W3T   36736    // 8192 [j][i]
#define WS_D2T   44928    // 8192 [k][j]
#define WS_DV    53120    // 131072
#define WS_G     184192   // 131072
#define WS_CONS  315264   // 1048576
#define WS_ABT   1363840  // 524288: ABt[c][tile64][j][2] (A includes b2)
#define WS_END_F 1888128
#define WSB_NXT8 ((size_t)WS_END_F * 4)      // 131072 B (u8 nxt[t][c])
#define WSB_CUR  (WSB_NXT8 + 131072)         // 65536 B (u32 cur[t])
#define WSB_CRX  (WSB_CUR + 65536)           // int CRX[8][256][12]

__device__ __forceinline__ unsigned int fn_compose(unsigned int hi, unsigned int lo) {
  unsigned int r = 0;
  #pragma unroll
  for (int x = 0; x < 8; ++x) {
    unsigned int m = (lo >> (3 * x)) & 7u;
    r |= ((hi >> (3 * m)) & 7u) << (3 * x);
  }
  return r;
}

// ---------------- prep: relayouts + gumbel + setup ----------------
__global__ void __launch_bounds__(256) k_prepAll(
    const float* __restrict__ pa, const float* __restrict__ gum,
    const int* __restrict__ edge,
    const float* __restrict__ W1, const float* __restrict__ b1,
    const float* __restrict__ W2, const float* __restrict__ W3,
    const float* __restrict__ W4,
    const float* __restrict__ D1, const float* __restrict__ d1,
    const float* __restrict__ D2, const float* __restrict__ D3,
    float* __restrict__ ws) {
  int b = blockIdx.x, tid = threadIdx.x;
  if (b < 128) {            // W2T[k][j] = W2[j][k]
    int e = b * 256 + tid;
    int k = e >> 7, j = e & 127;
    ws[WS_W2T + e] = W2[j * 256 + k];
  } else if (b < 160) {     // W3T[j][i] = W3[i][j]
    int e = (b - 128) * 256 + tid;
    int i = e & 63, j = e >> 6;
    ws[WS_W3T + e] = W3[i * 128 + j];
  } else if (b < 192) {     // D2T[k][j] = D2[j][k]
    int e = (b - 160) * 256 + tid;
    int j = e >> 7, k = e & 127;
    ws[WS_D2T + k * 64 + j] = D2[e];
  } else if (b < 704) {     // gumbels
    int e = (b - 192) * 256 + tid;
    float uu = gum[e];
    ws[WS_G + e] = -logf(-logf(uu + 1e-20f) + 1e-20f);
  } else {                  // setup
    {
      int k = tid;
      float acc = b1[k];
      #pragma unroll
      for (int i = 0; i < 8; ++i) acc = fmaf(pa[i], W1[k * 17 + i], acc);
      ws[WS_U + k] = acc;
      ws[WS_V + k] = W1[k * 17 + 8];
    }
    if (tid < 128) {
      float acc = d1[tid];
      #pragma unroll
      for (int i = 0; i < 8; ++i) acc = fmaf(pa[i], D1[tid * 9 + i], acc);
      ws[WS_UDC + tid] = acc;
      ws[WS_VDC + tid] = D1[tid * 9 + 8];
    }
    for (int e = tid; e < 2048; e += 256) {
      int cc = e >> 8, k = e & 255;
      ws[WS_W1ZT + e] = W1[k * 17 + 9 + cc];
    }
    for (int e = tid; e < 512; e += 256) {
      int k = e >> 3, z = e & 7;
      ws[WS_W4T + e] = W4[z * 64 + k];
      ws[WS_D3T + e] = D3[z * 64 + k];
    }
    if (tid < 64) ws[WS_A + tid] = ((tid >> 3) == (tid & 7)) ? 1.0f : 0.0f;
    __syncthreads();
    if (tid == 0) {
      for (int e = 0; e < 16; ++e) {
        int aa = edge[e], bb = edge[16 + e];
        ws[WS_A + aa * 8 + bb] = 1.0f;
        ws[WS_A + bb * 8 + aa] = 1.0f;
      }
    }
    __syncthreads();
    if (tid < 64) ws[WS_PEN + tid] = 1000.0f * (1.0f - ws[WS_A + tid]);
  }
}

// ---------------- diversity (LDS design): dv[t][8] ----------------
__global__ void __launch_bounds__(256) k_diversity(
    const float* __restrict__ times, const float* __restrict__ d2,
    const float* __restrict__ d3, float* __restrict__ ws) {
  __shared__ float h1dT[128][64];
  __shared__ float h2dT[64][64];
  int tid = threadIdx.x;
  int s = tid & 63, w = tid >> 6;
  int t = blockIdx.x * 64 + s;
  float last = times[T_STEPS - 1];
  float st = (last > 0.0f) ? times[t] / last : 0.0f;
  int j0 = __builtin_amdgcn_readfirstlane(w * 32);
  #pragma unroll
  for (int jj = 0; jj < 32; ++jj) {
    int j = j0 + jj;
    h1dT[j][s] = fmaxf(fmaf(st, ws[WS_VDC + j], ws[WS_UDC + j]), 0.0f);
  }
  __syncthreads();
  j0 = __builtin_amdgcn_readfirstlane(w * 16);
  float acc[16];
  #pragma unroll
  for (int jj = 0; jj < 16; ++jj) acc[jj] = d2[j0 + jj];
  #pragma unroll 4
  for (int k = 0; k < 128; ++k) {
    float h = h1dT[k][s];
    #pragma unroll
    for (int jj = 0; jj < 16; ++jj)
      acc[jj] = fmaf(ws[WS_D2T + k * 64 + j0 + jj], h, acc[jj]);
  }
  #pragma unroll
  for (int jj = 0; jj < 16; ++jj) h2dT[j0 + jj][s] = fmaxf(acc[jj], 0.0f);
  __syncthreads();
  if (tid < 64) {
    float a8[8];
    #pragma unroll
    for (int z = 0; z < 8; ++z) a8[z] = d3[z];
    #pragma unroll 4
    for (int k = 0; k < 64; ++k) {
      float h = h2dT[k][s];
      #pragma unroll
      for (int z = 0; z < 8; ++z) a8[z] = fmaf(ws[WS_D3T + k * 8 + z], h, a8[z]);
    }
    #pragma unroll
    for (int z = 0; z < 8; ++z) ws[WS_DV + t * 8 + z] = tanhf(a8[z]);
  }
}

// ---------------- AB precompute v2 ----------------
__global__ void __launch_bounds__(256) k_ab2(
    const float* __restrict__ times,
    const float* __restrict__ u_, const float* __restrict__ v_,
    const float* __restrict__ w1zt, const float* __restrict__ w2t,
    const float* __restrict__ b2,
    float* __restrict__ abt, int* __restrict__ crx) {
  __shared__ float s_au[256], s_av[256];
  __shared__ float s_pa[128], s_pb[128];
  __shared__ unsigned long long s_bal[4];
  int blk = blockIdx.x;
  int c = blk >> 8, tile = blk & 255;
  int tid = threadIdx.x;
  float last = times[T_STEPS - 1];
  float stL = (last > 0.0f) ? times[tile * 64] / last : 0.0f;
  float stR = (last > 0.0f) ? times[tile * 64 + 63] / last : 0.0f;
  {
    float uk = u_[tid] + w1zt[c * 256 + tid];
    float vk = v_[tid];
    float valL = fmaf(stL, vk, uk);
    float valR = fmaf(stR, vk, uk);
    float mn = fminf(valL, valR);
    float mx = fmaxf(valL, valR);
    bool act = (mn > 0.0f);
    bool cross = (!act) && (mx > 0.0f);
    s_au[tid] = act ? uk : 0.0f;
    s_av[tid] = act ? vk : 0.0f;
    unsigned long long bal = __ballot(cross);
    if ((tid & 63) == 0) s_bal[tid >> 6] = bal;
  }
  __syncthreads();
  if (tid == 0) {
    int cnt = 0;
    int list8[8];
    #pragma unroll
    for (int i = 0; i < 8; ++i) list8[i] = 0;
    #pragma unroll
    for (int w = 0; w < 4; ++w) {
      unsigned long long m = s_bal[w];
      while (m) {
        int bit = __ffsll(m) - 1;
        if (cnt < 8) list8[cnt] = w * 64 + bit;
        ++cnt;
        m &= (m - 1);
      }
    }
    crx[blk * 12] = cnt;
    #pragma unroll
    for (int i = 0; i < 8; ++i) crx[blk * 12 + 1 + i] = list8[i];
  }
  int j = tid & 127, half = tid >> 7;
  float A = 0.0f, B = 0.0f;
  const float* wrow = w2t + half * 128 * 128 + j;
  int kb = half * 128;
  #pragma unroll 4
  for (int kk = 0; kk < 128; ++kk) {
    float w = wrow[kk * 128];
    A = fmaf(s_au[kb + kk], w, A);
    B = fmaf(s_av[kb + kk], w, B);
  }
  if (half == 1) { s_pa[j] = A; s_pb[j] = B; }
  __syncthreads();
  if (half == 0) {
    abt[(size_t)blk * 256 + j * 2]     = A + s_pa[j] + b2[j];
    abt[(size_t)blk * 256 + j * 2 + 1] = B + s_pb[j];
  }
}

// ---------------- fused MLP v4: LDS-staged vector GEMM ----------------
#define H2S 68   // padded stride (16B-aligned rows, spread banks)
__global__ void __launch_bounds__(256, 2) k_mlp4(
    const float* __restrict__ times,
    const float* __restrict__ u_, const float* __restrict__ v_,
    const float* __restrict__ w1zt, const float* __restrict__ w2t,
    const float* __restrict__ abt, const int* __restrict__ crx,
    const float* __restrict__ w3t, const float* __restrict__ w4t,
    const float* __restrict__ b2, const float* __restrict__ b3,
    const float* __restrict__ b4,
    const float* __restrict__ dv, const float* __restrict__ gt,
    const float* __restrict__ pen, const float* __restrict__ tau,
    float* __restrict__ cons_out, unsigned char* __restrict__ nxt_out) {
  __shared__ float s_h2[128 * H2S];   // 34816 B
  __shared__ float s_w3[8192];        // 32768 B [j][i]
  __shared__ float s_w4[512];         // [i][z]
  __shared__ float s_st[64];
  __shared__ float s_hx[8][64];
  int tid = threadIdx.x;
  int blk = blockIdx.x;               // c*256 + tgrp
  int c = blk >> 8, tgrp = blk & 255;
  int t0g = tgrp * 64;
  float last = times[T_STEPS - 1];
  int cnt = crx[blk * 12];
  const float* w1c = w1zt + c * 256;

  // phase 0: st + hx (threads 0..63, t = tid)
  if (tid < 64) {
    float stv = (last > 0.0f) ? times[t0g + tid] / last : 0.0f;
    s_st[tid] = stv;
    if (cnt > 0 && cnt <= 8) {
      #pragma unroll
      for (int i = 0; i < 8; ++i) {
        int kki = crx[blk * 12 + 1 + i];
        float hx = fmaxf(fmaf(stv, v_[kki], u_[kki] + w1c[kki]), 0.0f);
        s_hx[i][tid] = (i < cnt) ? hx : 0.0f;
      }
    }
  }
  // w3/w4 copies (no dependence on phase 0)
  {
    const float4* w3v = (const float4*)w3t;
    float4* sw3v = (float4*)s_w3;
    #pragma unroll
    for (int r = 0; r < 8; ++r) sw3v[r * 256 + tid] = w3v[r * 256 + tid];
    if (tid < 128) ((float4*)s_w4)[tid] = ((const float4*)w4t)[tid];
  }
  __syncthreads();  // B1: s_st/s_hx ready

  // phase 1: stage h2[j][t]  (thread = (j, th): 32 t's each)
  {
    int j = tid & 127, th = tid >> 7;
    float2 abv = *(const float2*)(abt + (size_t)blk * 256 + j * 2);
    float A = abv.x, B = abv.y;
    if (cnt == 0) {
      #pragma unroll
      for (int i4 = 0; i4 < 8; ++i4) {
        int tl = th * 32 + i4 * 4;
        float4 hv;
        hv.x = fmaxf(fmaf(s_st[tl + 0], B, A), 0.0f);
        hv.y = fmaxf(fmaf(s_st[tl + 1], B, A), 0.0f);
        hv.z = fmaxf(fmaf(s_st[tl + 2], B, A), 0.0f);
        hv.w = fmaxf(fmaf(s_st[tl + 3], B, A), 0.0f);
        *(float4*)(s_h2 + j * H2S + tl) = hv;
      }
    } else if (cnt <= 8) {
      int kk[8];
      float w2v[8];
      #pragma unroll
      for (int i = 0; i < 8; ++i) {
        kk[i] = crx[blk * 12 + 1 + i];
        w2v[i] = (i < cnt) ? w2t[kk[i] * 128 + j] : 0.0f;
      }
      #pragma unroll 2
      for (int i4 = 0; i4 < 8; ++i4) {
        int tl = th * 32 + i4 * 4;
        float4 hv;
        #pragma unroll
        for (int q = 0; q < 4; ++q) {
          float x = fmaf(s_st[tl + q], B, A);
          #pragma unroll
          for (int i = 0; i < 8; ++i) x = fmaf(w2v[i], s_hx[i][tl + q], x);
          ((float*)&hv)[q] = fmaxf(x, 0.0f);
        }
        *(float4*)(s_h2 + j * H2S + tl) = hv;
      }
    } else {
      // exact brute-force (vanishingly rare)
      for (int tt = 0; tt < 32; ++tt) {
        int tl = th * 32 + tt;
        float stv = s_st[tl];
        float x = b2[j];
        for (int k = 0; k < 256; ++k) {
          float h1 = fmaxf(fmaf(stv, v_[k], u_[k] + w1c[k]), 0.0f);
          x = fmaf(w2t[k * 128 + j], h1, x);
        }
        s_h2[j * H2S + tl] = fmaxf(x, 0.0f);
      }
    }
  }
  __syncthreads();  // B2: h2 + w3 + w4 ready

  // phase 2: GEMM. thread = (tq, ihh): t = 2*tq+{0,1}, i = ihh*8..+8
  int tq = tid >> 3, ihh = tid & 7;
  int i0 = ihh * 8;
  float accA[8], accB[8];
  #pragma unroll
  for (int i = 0; i < 8; ++i) { float bi = b3[i0 + i]; accA[i] = bi; accB[i] = bi; }
  #pragma unroll 2
  for (int j = 0; j < 128; ++j) {
    float2 h = *(const float2*)(s_h2 + j * H2S + 2 * tq);
    const float4* w3p = (const float4*)(s_w3 + j * 64 + i0);
    float4 w0 = w3p[0], w1 = w3p[1];
    accA[0] = fmaf(w0.x, h.x, accA[0]); accB[0] = fmaf(w0.x, h.y, accB[0]);
    accA[1] = fmaf(w0.y, h.x, accA[1]); accB[1] = fmaf(w0.y, h.y, accB[1]);
    accA[2] = fmaf(w0.z, h.x, accA[2]); accB[2] = fmaf(w0.z, h.y, accB[2]);
    accA[3] = fmaf(w0.w, h.x, accA[3]); accB[3] = fmaf(w0.w, h.y, accB[3]);
    accA[4] = fmaf(w1.x, h.x, accA[4]); accB[4] = fmaf(w1.x, h.y, accB[4]);
    accA[5] = fmaf(w1.y, h.x, accA[5]); accB[5] = fmaf(w1.y, h.y, accB[5]);
    accA[6] = fmaf(w1.z, h.x, accA[6]); accB[6] = fmaf(w1.z, h.y, accB[6]);
    accA[7] = fmaf(w1.w, h.x, accA[7]); accB[7] = fmaf(w1.w, h.y, accB[7]);
  }

  // layer 4 partials over own 8 i's
  float pA[8], pB[8];
  #pragma unroll
  for (int z = 0; z < 8; ++z) {
    float b4z = (ihh == 0) ? b4[z] : 0.0f;
    pA[z] = b4z; pB[z] = b4z;
  }
  #pragma unroll
  for (int i = 0; i < 8; ++i) {
    float h3A = fmaxf(accA[i], 0.0f);
    float h3B = fmaxf(accB[i], 0.0f);
    #pragma unroll
    for (int z = 0; z < 8; ++z) {
      float w4 = s_w4[(i0 + i) * 8 + z];
      pA[z] = fmaf(w4, h3A, pA[z]);
      pB[z] = fmaf(w4, h3B, pB[z]);
    }
  }
  // butterfly all-reduce across the 8 ihh lanes
  #pragma unroll
  for (int d = 1; d < 8; d <<= 1) {
    #pragma unroll
    for (int z = 0; z < 8; ++z) {
      pA[z] += __shfl_xor(pA[z], d);
      pB[z] += __shfl_xor(pB[z], d);
    }
  }
  // select own z = ihh (static chain, no dynamic reg index)
  float a4A = pA[0], a4B = pB[0];
  #pragma unroll
  for (int z = 1; z < 8; ++z) {
    if (ihh == z) { a4A = pA[z]; a4B = pB[z]; }
  }

  float sgn = (tau[0] > 0.0f) ? 1.0f : -1.0f;
  float penv = pen[c * 8 + ihh];
  #pragma unroll
  for (int tt = 0; tt < 2; ++tt) {
    int t = t0g + 2 * tq + tt;
    float a4 = (tt == 0) ? a4A : a4B;
    float dvv = dv[(size_t)t * 8 + ihh];
    float gvv = gt[(size_t)t * 8 + ihh];
    float lg = fmaf(0.2f, dvv, a4) - penv;
    float yv = (lg + gvv) * sgn;
    cons_out[((size_t)t * 8 + c) * 8 + ihh] = lg;
    float bv = yv; int bz = ihh;
    #pragma unroll
    for (int d = 1; d < 8; d <<= 1) {
      float pv = __shfl_xor(bv, d);
      int pz = __shfl_xor(bz, d);
      if (pv > bv || (pv == bv && pz < bz)) { bv = pv; bz = pz; }
    }
    if (ihh == 0) nxt_out[t * 8 + c] = (unsigned char)bz;
  }
}

// ---------------- phase C: parallel prefix, 1024 threads x 16 steps ----------------
__global__ void __launch_bounds__(1024) k_phaseC(float* __restrict__ ws, float* __restrict__ d_out) {
  int tid = threadIdx.x;
  const unsigned char* nxt8 = (const unsigned char*)ws + WSB_NXT8;
  unsigned int* cur_arr = (unsigned int*)((char*)ws + WSB_CUR);
  const unsigned int IDENT = 0x00FAC688u;
  unsigned int f[16];
  int t0 = tid * 16;
  unsigned int F = IDENT;
  #pragma unroll
  for (int i = 0; i < 16; ++i) {
    uint2 b = *(const uint2*)(nxt8 + (size_t)(t0 + i) * 8);
    unsigned int fn = 0;
    #pragma unroll
    for (int q = 0; q < 4; ++q) fn |= ((b.x >> (8 * q)) & 7u) << (3 * q);
    #pragma unroll
    for (int q = 0; q < 4; ++q) fn |= ((b.y >> (8 * q)) & 7u) << (3 * (q + 4));
    f[i] = fn;
    F = fn_compose(fn, F);
  }
  __shared__ unsigned int sc[1024];
  sc[tid] = F;
  __syncthreads();
  #pragma unroll
  for (int d = 1; d < 1024; d <<= 1) {
    unsigned int v = sc[tid];
    unsigned int p = (tid >= d) ? sc[tid - d] : 0u;
    unsigned int nv = (tid >= d) ? fn_compose(v, p) : v;
    __syncthreads();
    sc[tid] = nv;
    __syncthreads();
  }
  unsigned int E = (tid == 0) ? IDENT : sc[tid - 1];
  unsigned int state = E & 7u;
  #pragma unroll
  for (int i = 0; i < 16; ++i) {
    int tt = t0 + i;
    cur_arr[tt] = state;
    unsigned int nx = (f[i] >> (3 * state)) & 7u;
    d_out[131072 + tt] = (float)nx;
    state = nx;
  }
}

// ---------------- gather ----------------
__global__ void k_gather(const float* __restrict__ ws, float* __restrict__ d_out) {
  int idx = blockIdx.x * 256 + threadIdx.x;
  const unsigned int* cur_arr = (const unsigned int*)((const char*)ws + WSB_CUR);
  int t = idx >> 3, z = idx & 7;
  unsigned int cur = cur_arr[t];
  d_out[idx] = ws[WS_CONS + (t * 8 + (int)cur) * 8 + z];
}

extern "C" void kernel_launch(void* const* d_in, const int* in_sizes, int n_in,
                              void* d_out, int out_size, void* d_ws, size_t ws_size,
                              hipStream_t stream) {
  const float* pa    = (const float*)d_in[0];
  const float* times = (const float*)d_in[1];
  const float* gum   = (const float*)d_in[2];
  const int*   edge  = (const int*)d_in[3];
  const float* W1  = (const float*)d_in[4];
  const float* b1  = (const float*)d_in[5];
  const float* W2  = (const float*)d_in[6];
  const float* b2  = (const float*)d_in[7];
  const float* W3  = (const float*)d_in[8];
  const float* b3  = (const float*)d_in[9];
  const float* W4  = (const float*)d_in[10];
  const float* b4  = (const float*)d_in[11];
  const float* D1  = (const float*)d_in[12];
  const float* d1v = (const float*)d_in[13];
  const float* D2  = (const float*)d_in[14];
  const float* d2v = (const float*)d_in[15];
  const float* D3  = (const float*)d_in[16];
  const float* d3v = (const float*)d_in[17];
  const float* tau = (const float*)d_in[18];
  float* ws = (float*)d_ws;
  float* out = (float*)d_out;
  int* crx = (int*)((char*)d_ws + WSB_CRX);

  k_prepAll<<<705, 256, 0, stream>>>(pa, gum, edge, W1, b1, W2, W3, W4,
                                     D1, d1v, D2, D3, ws);
  k_diversity<<<256, 256, 0, stream>>>(times, d2v, d3v, ws);
  k_ab2<<<2048, 256, 0, stream>>>(times, ws + WS_U, ws + WS_V, ws + WS_W1ZT,
                                  ws + WS_W2T, b2, ws + WS_ABT, crx);
  k_mlp4<<<2048, 256, 0, stream>>>(times, ws + WS_U, ws + WS_V, ws + WS_W1ZT,
                                   ws + WS_W2T, ws + WS_ABT, crx,
                                   ws + WS_W3T, ws + WS_W4T, b2, b3, b4,
                                   ws + WS_DV, ws + WS_G, ws + WS_PEN, tau,
                                   ws + WS_CONS, (unsigned char*)ws + WSB_NXT8);
  k_phaseC<<<1, 1024, 0, stream>>>(ws, out);
  k_gather<<<512, 256, 0, stream>>>(ws, out);
}

// Round 11
// 114.662 us; speedup vs baseline: 1.0090x; 1.0090x over previous
//
#include <hip/hip_runtime.h>
#include <cstdint>

#define T_STEPS 16384

// ---- workspace float offsets ----
#define WS_U     0        // 256
#define WS_V     256      // 256
#define WS_W1ZT  512      // 2048 [c][k]
#define WS_PEN   2560     // 64
#define WS_A     2624     // 64
#define WS_W4T   2688     // 512 [i][z]
#define WS_UDC   3200     // 128
#define WS_VDC   3328     // 128
#define WS_D3T   3456     // 512 [k][z]
#define WS_W2T   3968     // 32768 [k][j] 256x128
#define WS_W3T   36736    // 8192 [j][i]
#define WS_D2T   44928    // 8192 [k][j]
#define WS_DV    53120    // 131072
#define WS_G     184192   // 131072
#define WS_CONS  315264   // 1048576
#define WS_ABT   1363840  // 524288: ABt[c][tile64][j][2] (A includes b2)
#define WS_A4LR  1888128  // 32768: a4 endpoints [blk][16] (L:0..7, R:8..15)
#define WS_END_F 1920896
#define WSB_NXT8 ((size_t)WS_END_F * 4)      // 131072 B (u8 nxt[t][c])
#define WSB_CUR  (WSB_NXT8 + 131072)         // 65536 B (u32 cur[t])
#define WSB_CRX  (WSB_CUR + 65536)           // int CRX[2048][12]: cnt, k[8], flag@9

__device__ __forceinline__ unsigned int fn_compose(unsigned int hi, unsigned int lo) {
  unsigned int r = 0;
  #pragma unroll
  for (int x = 0; x < 8; ++x) {
    unsigned int m = (lo >> (3 * x)) & 7u;
    r |= ((hi >> (3 * m)) & 7u) << (3 * x);
  }
  return r;
}

// ---------------- prep: relayouts + gumbel + setup ----------------
__global__ void __launch_bounds__(256) k_prepAll(
    const float* __restrict__ pa, const float* __restrict__ gum,
    const int* __restrict__ edge,
    const float* __restrict__ W1, const float* __restrict__ b1,
    const float* __restrict__ W2, const float* __restrict__ W3,
    const float* __restrict__ W4,
    const float* __restrict__ D1, const float* __restrict__ d1,
    const float* __restrict__ D2, const float* __restrict__ D3,
    float* __restrict__ ws) {
  int b = blockIdx.x, tid = threadIdx.x;
  if (b < 128) {            // W2T[k][j] = W2[j][k]
    int e = b * 256 + tid;
    int k = e >> 7, j = e & 127;
    ws[WS_W2T + e] = W2[j * 256 + k];
  } else if (b < 160) {     // W3T[j][i] = W3[i][j]
    int e = (b - 128) * 256 + tid;
    int i = e & 63, j = e >> 6;
    ws[WS_W3T + e] = W3[i * 128 + j];
  } else if (b < 192) {     // D2T[k][j] = D2[j][k]
    int e = (b - 160) * 256 + tid;
    int j = e >> 7, k = e & 127;
    ws[WS_D2T + k * 64 + j] = D2[e];
  } else if (b < 704) {     // gumbels
    int e = (b - 192) * 256 + tid;
    float uu = gum[e];
    ws[WS_G + e] = -logf(-logf(uu + 1e-20f) + 1e-20f);
  } else {                  // setup
    {
      int k = tid;
      float acc = b1[k];
      #pragma unroll
      for (int i = 0; i < 8; ++i) acc = fmaf(pa[i], W1[k * 17 + i], acc);
      ws[WS_U + k] = acc;
      ws[WS_V + k] = W1[k * 17 + 8];
    }
    if (tid < 128) {
      float acc = d1[tid];
      #pragma unroll
      for (int i = 0; i < 8; ++i) acc = fmaf(pa[i], D1[tid * 9 + i], acc);
      ws[WS_UDC + tid] = acc;
      ws[WS_VDC + tid] = D1[tid * 9 + 8];
    }
    for (int e = tid; e < 2048; e += 256) {
      int cc = e >> 8, k = e & 255;
      ws[WS_W1ZT + e] = W1[k * 17 + 9 + cc];
    }
    for (int e = tid; e < 512; e += 256) {
      int k = e >> 3, z = e & 7;
      ws[WS_W4T + e] = W4[z * 64 + k];
      ws[WS_D3T + e] = D3[z * 64 + k];
    }
    if (tid < 64) ws[WS_A + tid] = ((tid >> 3) == (tid & 7)) ? 1.0f : 0.0f;
    __syncthreads();
    if (tid == 0) {
      for (int e = 0; e < 16; ++e) {
        int aa = edge[e], bb = edge[16 + e];
        ws[WS_A + aa * 8 + bb] = 1.0f;
        ws[WS_A + bb * 8 + aa] = 1.0f;
      }
    }
    __syncthreads();
    if (tid < 64) ws[WS_PEN + tid] = 1000.0f * (1.0f - ws[WS_A + tid]);
  }
}

// ---------------- diversity (LDS design): dv[t][8] ----------------
__global__ void __launch_bounds__(256) k_diversity(
    const float* __restrict__ times, const float* __restrict__ d2,
    const float* __restrict__ d3, float* __restrict__ ws) {
  __shared__ float h1dT[128][64];
  __shared__ float h2dT[64][64];
  int tid = threadIdx.x;
  int s = tid & 63, w = tid >> 6;
  int t = blockIdx.x * 64 + s;
  float last = times[T_STEPS - 1];
  float st = (last > 0.0f) ? times[t] / last : 0.0f;
  int j0 = __builtin_amdgcn_readfirstlane(w * 32);
  #pragma unroll
  for (int jj = 0; jj < 32; ++jj) {
    int j = j0 + jj;
    h1dT[j][s] = fmaxf(fmaf(st, ws[WS_VDC + j], ws[WS_UDC + j]), 0.0f);
  }
  __syncthreads();
  j0 = __builtin_amdgcn_readfirstlane(w * 16);
  float acc[16];
  #pragma unroll
  for (int jj = 0; jj < 16; ++jj) acc[jj] = d2[j0 + jj];
  #pragma unroll 4
  for (int k = 0; k < 128; ++k) {
    float h = h1dT[k][s];
    #pragma unroll
    for (int jj = 0; jj < 16; ++jj)
      acc[jj] = fmaf(ws[WS_D2T + k * 64 + j0 + jj], h, acc[jj]);
  }
  #pragma unroll
  for (int jj = 0; jj < 16; ++jj) h2dT[j0 + jj][s] = fmaxf(acc[jj], 0.0f);
  __syncthreads();
  if (tid < 64) {
    float a8[8];
    #pragma unroll
    for (int z = 0; z < 8; ++z) a8[z] = d3[z];
    #pragma unroll 4
    for (int k = 0; k < 64; ++k) {
      float h = h2dT[k][s];
      #pragma unroll
      for (int z = 0; z < 8; ++z) a8[z] = fmaf(ws[WS_D3T + k * 8 + z], h, a8[z]);
    }
    #pragma unroll
    for (int z = 0; z < 8; ++z) ws[WS_DV + t * 8 + z] = tanhf(a8[z]);
  }
}

// ---------------- AB precompute v3: + endpoint evals + clean-tile flag ----------------
__global__ void __launch_bounds__(256) k_ab3(
    const float* __restrict__ times,
    const float* __restrict__ u_, const float* __restrict__ v_,
    const float* __restrict__ w1zt, const float* __restrict__ w2t,
    const float* __restrict__ w3t, const float* __restrict__ w4t,
    const float* __restrict__ b2, const float* __restrict__ b3,
    const float* __restrict__ b4,
    float* __restrict__ abt, int* __restrict__ crx,
    float* __restrict__ a4lr) {
  __shared__ float s_au[256], s_av[256];
  __shared__ float s_pa[128], s_pb[128];
  __shared__ unsigned long long s_bal[4];
  __shared__ float s_h2L[128], s_h2R[128];
  __shared__ float s_h3L[64], s_h3R[64];
  __shared__ int s_dirty, s_cnt;
  int blk = blockIdx.x;
  int c = blk >> 8, tile = blk & 255;
  int tid = threadIdx.x;
  float last = times[T_STEPS - 1];
  float stL = (last > 0.0f) ? times[tile * 64] / last : 0.0f;
  float stR = (last > 0.0f) ? times[tile * 64 + 63] / last : 0.0f;
  {
    float uk = u_[tid] + w1zt[c * 256 + tid];
    float vk = v_[tid];
    float valL = fmaf(stL, vk, uk);
    float valR = fmaf(stR, vk, uk);
    float mn = fminf(valL, valR);
    float mx = fmaxf(valL, valR);
    bool act = (mn > 0.0f);
    bool cross = (!act) && (mx > 0.0f);
    s_au[tid] = act ? uk : 0.0f;
    s_av[tid] = act ? vk : 0.0f;
    unsigned long long bal = __ballot(cross);
    if ((tid & 63) == 0) s_bal[tid >> 6] = bal;
  }
  if (tid == 0) s_dirty = 0;
  __syncthreads();
  if (tid == 0) {
    int cnt = 0;
    int list8[8];
    #pragma unroll
    for (int i = 0; i < 8; ++i) list8[i] = 0;
    #pragma unroll
    for (int w = 0; w < 4; ++w) {
      unsigned long long m = s_bal[w];
      while (m) {
        int bit = __ffsll(m) - 1;
        if (cnt < 8) list8[cnt] = w * 64 + bit;
        ++cnt;
        m &= (m - 1);
      }
    }
    crx[blk * 12] = cnt;
    s_cnt = cnt;
    #pragma unroll
    for (int i = 0; i < 8; ++i) crx[blk * 12 + 1 + i] = list8[i];
  }
  // masked matvec (A,B per j)
  int j = tid & 127, half = tid >> 7;
  float A = 0.0f, B = 0.0f;
  const float* wrow = w2t + half * 128 * 128 + j;
  int kb = half * 128;
  #pragma unroll 4
  for (int kk = 0; kk < 128; ++kk) {
    float w = wrow[kk * 128];
    A = fmaf(s_au[kb + kk], w, A);
    B = fmaf(s_av[kb + kk], w, B);
  }
  if (half == 1) { s_pa[j] = A; s_pb[j] = B; }
  __syncthreads();
  if (half == 0) {
    float Af = A + s_pa[j] + b2[j];
    float Bf = B + s_pb[j];
    abt[(size_t)blk * 256 + j * 2]     = Af;
    abt[(size_t)blk * 256 + j * 2 + 1] = Bf;
    float preL = fmaf(stL, Bf, Af);
    float preR = fmaf(stR, Bf, Af);
    if ((preL > 0.0f) != (preR > 0.0f)) atomicOr(&s_dirty, 1);
    s_h2L[j] = fmaxf(preL, 0.0f);
    s_h2R[j] = fmaxf(preR, 0.0f);
  }
  __syncthreads();
  // h3 endpoints (valid when cnt==0; only used then)
  if (tid < 64) {
    float aL = b3[tid], aR = b3[tid];
    #pragma unroll 4
    for (int j2 = 0; j2 < 128; ++j2) {
      float w = w3t[j2 * 64 + tid];
      aL = fmaf(w, s_h2L[j2], aL);
      aR = fmaf(w, s_h2R[j2], aR);
    }
    if ((aL > 0.0f) != (aR > 0.0f)) atomicOr(&s_dirty, 1);
    s_h3L[tid] = fmaxf(aL, 0.0f);
    s_h3R[tid] = fmaxf(aR, 0.0f);
  }
  __syncthreads();
  if (tid < 8) {
    float aL = b4[tid], aR = b4[tid];
    #pragma unroll 8
    for (int i = 0; i < 64; ++i) {
      float w = w4t[i * 8 + tid];
      aL = fmaf(w, s_h3L[i], aL);
      aR = fmaf(w, s_h3R[i], aR);
    }
    a4lr[blk * 16 + tid] = aL;
    a4lr[blk * 16 + 8 + tid] = aR;
  }
  if (tid == 0)
    crx[blk * 12 + 9] = (s_cnt == 0 && s_dirty == 0) ? 1 : 0;
}

// ---------------- fused MLP (R8 structure) + clean-tile lerp fast path ----------------
__global__ void __launch_bounds__(512, 8) k_mlp(
    const float* __restrict__ times,
    const float* __restrict__ u_, const float* __restrict__ v_,
    const float* __restrict__ w1zt, const float* __restrict__ w2t,
    const float* __restrict__ abt, const int* __restrict__ crx,
    const float* __restrict__ a4lr,
    const float* __restrict__ w3t, const float* __restrict__ w4t,
    const float* __restrict__ b2, const float* __restrict__ b3,
    const float* __restrict__ b4,
    const float* __restrict__ dv, const float* __restrict__ gt,
    const float* __restrict__ pen, const float* __restrict__ tau,
    float* __restrict__ cons_out, unsigned char* __restrict__ nxt_out) {
  __shared__ float part[2][3][8][64];  // 12KB
  int tid = threadIdx.x;
  int lane = tid & 63;
  int wv = __builtin_amdgcn_readfirstlane(tid >> 6);  // 0..7
  int iq = wv & 3;        // i-quarter
  int cp = wv >> 2;       // c within pair
  int tgrp = blockIdx.x >> 2;
  int c = (blockIdx.x & 3) * 2 + cp;
  int t = tgrp * 64 + lane;
  float last = times[T_STEPS - 1];
  float st = (last > 0.0f) ? times[t] / last : 0.0f;
  const float* w1c = w1zt + c * 256;
  int blk = c * 256 + tgrp;
  int abase = blk * 256;
  int cbase = blk * 12;
  int flag = crx[cbase + 9];
  int cnt = crx[cbase];

  float p[8];
  #pragma unroll
  for (int z = 0; z < 8; ++z) p[z] = 0.0f;

  if (!flag) {
    float acc[16];
    #pragma unroll
    for (int i = 0; i < 16; ++i) acc[i] = b3[iq * 16 + i];
    const float* w3 = w3t + iq * 16;

    if (cnt == 0) {
      #pragma unroll 4
      for (int j = 0; j < 128; ++j) {
        float A = abt[abase + j * 2];
        float B = abt[abase + j * 2 + 1];
        float h2 = fmaxf(fmaf(st, B, A), 0.0f);
        #pragma unroll
        for (int i = 0; i < 16; ++i)
          acc[i] = fmaf(w3[j * 64 + i], h2, acc[i]);
      }
    } else if (cnt <= 8) {
      int kk[8];
      #pragma unroll
      for (int i = 0; i < 8; ++i) kk[i] = (i < cnt) ? crx[cbase + 1 + i] : 0;
      float hx[8];
      #pragma unroll
      for (int i = 0; i < 8; ++i)
        hx[i] = (i < cnt) ? fmaxf(fmaf(st, v_[kk[i]], u_[kk[i]] + w1c[kk[i]]), 0.0f) : 0.0f;
      #pragma unroll 2
      for (int j = 0; j < 128; ++j) {
        float A = abt[abase + j * 2];
        float B = abt[abase + j * 2 + 1];
        float h2p = fmaf(st, B, A);
        #pragma unroll
        for (int i = 0; i < 8; ++i)
          h2p = fmaf(hx[i], w2t[kk[i] * 128 + j], h2p);
        float h2 = fmaxf(h2p, 0.0f);
        #pragma unroll
        for (int i = 0; i < 16; ++i)
          acc[i] = fmaf(w3[j * 64 + i], h2, acc[i]);
      }
    } else {
      // exact brute-force (vanishingly rare)
      for (int j = 0; j < 128; ++j) {
        float h2p = b2[j];
        for (int k = 0; k < 256; ++k) {
          float h1 = fmaxf(fmaf(st, v_[k], u_[k] + w1c[k]), 0.0f);
          h2p = fmaf(w2t[k * 128 + j], h1, h2p);
        }
        float h2 = fmaxf(h2p, 0.0f);
        #pragma unroll
        for (int i = 0; i < 16; ++i)
          acc[i] = fmaf(w3[j * 64 + i], h2, acc[i]);
      }
    }

    // layer 4 partials over own 16 h3's
    #pragma unroll
    for (int z = 0; z < 8; ++z) p[z] = (iq == 0) ? b4[z] : 0.0f;
    #pragma unroll 4
    for (int i = 0; i < 16; ++i) {
      float h3 = fmaxf(acc[i], 0.0f);
      #pragma unroll
      for (int z = 0; z < 8; ++z)
        p[z] = fmaf(w4t[(iq * 16 + i) * 8 + z], h3, p[z]);
    }
    if (iq > 0) {
      #pragma unroll
      for (int z = 0; z < 8; ++z) part[cp][iq - 1][z][lane] = p[z];
    }
  }
  __syncthreads();
  if (iq == 0) {
    float a4[8];
    if (flag) {
      float frac = (float)lane * (1.0f / 63.0f);
      #pragma unroll
      for (int z = 0; z < 8; ++z) {
        float L = a4lr[blk * 16 + z];
        float R = a4lr[blk * 16 + 8 + z];
        a4[z] = fmaf(frac, R - L, L);
      }
    } else {
      #pragma unroll
      for (int z = 0; z < 8; ++z)
        a4[z] = p[z] + part[cp][0][z][lane] + part[cp][1][z][lane] + part[cp][2][z][lane];
    }
    float4 dv0 = *(const float4*)(dv + (size_t)t * 8);
    float4 dv1 = *(const float4*)(dv + (size_t)t * 8 + 4);
    float4 g0  = *(const float4*)(gt + (size_t)t * 8);
    float4 g1  = *(const float4*)(gt + (size_t)t * 8 + 4);
    float dvv[8] = {dv0.x, dv0.y, dv0.z, dv0.w, dv1.x, dv1.y, dv1.z, dv1.w};
    float gv[8]  = {g0.x, g0.y, g0.z, g0.w, g1.x, g1.y, g1.z, g1.w};
    float sgn = (tau[0] > 0.0f) ? 1.0f : -1.0f;
    float cons[8];
    float best = 0.0f; int bz = 0;
    #pragma unroll
    for (int z = 0; z < 8; ++z) {
      float lg = fmaf(0.2f, dvv[z], a4[z]) - pen[c * 8 + z];
      cons[z] = lg;
      float yv = (lg + gv[z]) * sgn;
      if (z == 0) { best = yv; bz = 0; }
      else if (yv > best) { best = yv; bz = z; }
    }
    float* co = cons_out + ((size_t)t * 8 + c) * 8;
    *(float4*)co = make_float4(cons[0], cons[1], cons[2], cons[3]);
    *(float4*)(co + 4) = make_float4(cons[4], cons[5], cons[6], cons[7]);
    nxt_out[t * 8 + c] = (unsigned char)bz;
  }
}

// ---------------- phase C: parallel prefix, 1024 threads x 16 steps ----------------
__global__ void __launch_bounds__(1024) k_phaseC(float* __restrict__ ws, float* __restrict__ d_out) {
  int tid = threadIdx.x;
  const unsigned char* nxt8 = (const unsigned char*)ws + WSB_NXT8;
  unsigned int* cur_arr = (unsigned int*)((char*)ws + WSB_CUR);
  const unsigned int IDENT = 0x00FAC688u;
  unsigned int f[16];
  int t0 = tid * 16;
  unsigned int F = IDENT;
  #pragma unroll
  for (int i = 0; i < 16; ++i) {
    uint2 b = *(const uint2*)(nxt8 + (size_t)(t0 + i) * 8);
    unsigned int fn = 0;
    #pragma unroll
    for (int q = 0; q < 4; ++q) fn |= ((b.x >> (8 * q)) & 7u) << (3 * q);
    #pragma unroll
    for (int q = 0; q < 4; ++q) fn |= ((b.y >> (8 * q)) & 7u) << (3 * (q + 4));
    f[i] = fn;
    F = fn_compose(fn, F);
  }
  __shared__ unsigned int sc[1024];
  sc[tid] = F;
  __syncthreads();
  #pragma unroll
  for (int d = 1; d < 1024; d <<= 1) {
    unsigned int v = sc[tid];
    unsigned int p = (tid >= d) ? sc[tid - d] : 0u;
    unsigned int nv = (tid >= d) ? fn_compose(v, p) : v;
    __syncthreads();
    sc[tid] = nv;
    __syncthreads();
  }
  unsigned int E = (tid == 0) ? IDENT : sc[tid - 1];
  unsigned int state = E & 7u;
  #pragma unroll
  for (int i = 0; i < 16; ++i) {
    int tt = t0 + i;
    cur_arr[tt] = state;
    unsigned int nx = (f[i] >> (3 * state)) & 7u;
    d_out[131072 + tt] = (float)nx;
    state = nx;
  }
}

// ---------------- gather ----------------
__global__ void k_gather(const float* __restrict__ ws, float* __restrict__ d_out) {
  int idx = blockIdx.x * 256 + threadIdx.x;
  const unsigned int* cur_arr = (const unsigned int*)((const char*)ws + WSB_CUR);
  int t = idx >> 3, z = idx & 7;
  unsigned int cur = cur_arr[t];
  d_out[idx] = ws[WS_CONS + (t * 8 + (int)cur) * 8 + z];
}

extern "C" void kernel_launch(void* const* d_in, const int* in_sizes, int n_in,
                              void* d_out, int out_size, void* d_ws, size_t ws_size,
                              hipStream_t stream) {
  const float* pa    = (const float*)d_in[0];
  const float* times = (const float*)d_in[1];
  const float* gum   = (const float*)d_in[2];
  const int*   edge  = (const int*)d_in[3];
  const float* W1  = (const float*)d_in[4];
  const float* b1  = (const float*)d_in[5];
  const float* W2  = (const float*)d_in[6];
  const float* b2  = (const float*)d_in[7];
  const float* W3  = (const float*)d_in[8];
  const float* b3  = (const float*)d_in[9];
  const float* W4  = (const float*)d_in[10];
  const float* b4  = (const float*)d_in[11];
  const float* D1  = (const float*)d_in[12];
  const float* d1v = (const float*)d_in[13];
  const float* D2  = (const float*)d_in[14];
  const float* d2v = (const float*)d_in[15];
  const float* D3  = (const float*)d_in[16];
  const float* d3v = (const float*)d_in[17];
  const float* tau = (const float*)d_in[18];
  float* ws = (float*)d_ws;
  float* out = (float*)d_out;
  int* crx = (int*)((char*)d_ws + WSB_CRX);

  k_prepAll<<<705, 256, 0, stream>>>(pa, gum, edge, W1, b1, W2, W3, W4,
                                     D1, d1v, D2, D3, ws);
  k_diversity<<<256, 256, 0, stream>>>(times, d2v, d3v, ws);
  k_ab3<<<2048, 256, 0, stream>>>(times, ws + WS_U, ws + WS_V, ws + WS_W1ZT,
                                  ws + WS_W2T, ws + WS_W3T, ws + WS_W4T,
                                  b2, b3, b4, ws + WS_ABT, crx, ws + WS_A4LR);
  k_mlp<<<1024, 512, 0, stream>>>(times, ws + WS_U, ws + WS_V, ws + WS_W1ZT,
                                  ws + WS_W2T, ws + WS_ABT, crx, ws + WS_A4LR,
                                  ws + WS_W3T, ws + WS_W4T, b2, b3, b4,
                                  ws + WS_DV, ws + WS_G, ws + WS_PEN, tau,
                                  ws + WS_CONS, (unsigned char*)ws + WSB_NXT8);
  k_phaseC<<<1, 1024, 0, stream>>>(ws, out);
  k_gather<<<512, 256, 0, stream>>>(ws, out);
}

// Round 12
// 103.946 us; speedup vs baseline: 1.1131x; 1.1031x over previous
//
#include <hip/hip_runtime.h>
#include <cstdint>

#define T_STEPS 16384

// ---- workspace float offsets ----
#define WS_U     0        // 256
#define WS_V     256      // 256
#define WS_W1ZT  512      // 2048 [c][k]
#define WS_PEN   2560     // 64
#define WS_A     2624     // 64
#define WS_W4T   2688     // 512 [i][z]
#define WS_UDC   3200     // 128
#define WS_VDC   3328     // 128
#define WS_D3T   3456     // 512 [k][z]
#define WS_W2T   3968     // 32768 [k][j] 256x128
#define WS_W3T   36736    // 8192 [j][i]
#define WS_D2T   44928    // 8192 [k][j]
#define WS_DV    53120    // 131072
#define WS_G     184192   // 131072
#define WS_CONS  315264   // 1048576
#define WS_ABT   1363840  // 524288: ABt[c][tile64][j][2] (A includes b2)
#define WS_A4LR  1888128  // 32768: a4 endpoints [blk][16] (L:0..7, R:8..15)
#define WS_END_F 1920896
#define WSB_NXT8 ((size_t)WS_END_F * 4)      // 131072 B (u8 nxt[t][c])
#define WSB_CUR  (WSB_NXT8 + 131072)         // 65536 B (u32 cur[t])
#define WSB_CRX  (WSB_CUR + 65536)           // int CRX[2048][12]: cnt, k[8], flag@9

__device__ __forceinline__ unsigned int fn_compose(unsigned int hi, unsigned int lo) {
  unsigned int r = 0;
  #pragma unroll
  for (int x = 0; x < 8; ++x) {
    unsigned int m = (lo >> (3 * x)) & 7u;
    r |= ((hi >> (3 * m)) & 7u) << (3 * x);
  }
  return r;
}

// ---------------- prep: relayouts + gumbel + setup ----------------
__global__ void __launch_bounds__(256) k_prepAll(
    const float* __restrict__ pa, const float* __restrict__ gum,
    const int* __restrict__ edge,
    const float* __restrict__ W1, const float* __restrict__ b1,
    const float* __restrict__ W2, const float* __restrict__ W3,
    const float* __restrict__ W4,
    const float* __restrict__ D1, const float* __restrict__ d1,
    const float* __restrict__ D2, const float* __restrict__ D3,
    float* __restrict__ ws) {
  int b = blockIdx.x, tid = threadIdx.x;
  if (b < 128) {            // W2T[k][j] = W2[j][k]
    int e = b * 256 + tid;
    int k = e >> 7, j = e & 127;
    ws[WS_W2T + e] = W2[j * 256 + k];
  } else if (b < 160) {     // W3T[j][i] = W3[i][j]
    int e = (b - 128) * 256 + tid;
    int i = e & 63, j = e >> 6;
    ws[WS_W3T + e] = W3[i * 128 + j];
  } else if (b < 192) {     // D2T[k][j] = D2[j][k]
    int e = (b - 160) * 256 + tid;
    int j = e >> 7, k = e & 127;
    ws[WS_D2T + k * 64 + j] = D2[e];
  } else if (b < 704) {     // gumbels
    int e = (b - 192) * 256 + tid;
    float uu = gum[e];
    ws[WS_G + e] = -logf(-logf(uu + 1e-20f) + 1e-20f);
  } else {                  // setup
    {
      int k = tid;
      float acc = b1[k];
      #pragma unroll
      for (int i = 0; i < 8; ++i) acc = fmaf(pa[i], W1[k * 17 + i], acc);
      ws[WS_U + k] = acc;
      ws[WS_V + k] = W1[k * 17 + 8];
    }
    if (tid < 128) {
      float acc = d1[tid];
      #pragma unroll
      for (int i = 0; i < 8; ++i) acc = fmaf(pa[i], D1[tid * 9 + i], acc);
      ws[WS_UDC + tid] = acc;
      ws[WS_VDC + tid] = D1[tid * 9 + 8];
    }
    for (int e = tid; e < 2048; e += 256) {
      int cc = e >> 8, k = e & 255;
      ws[WS_W1ZT + e] = W1[k * 17 + 9 + cc];
    }
    for (int e = tid; e < 512; e += 256) {
      int k = e >> 3, z = e & 7;
      ws[WS_W4T + e] = W4[z * 64 + k];
      ws[WS_D3T + e] = D3[z * 64 + k];
    }
    if (tid < 64) ws[WS_A + tid] = ((tid >> 3) == (tid & 7)) ? 1.0f : 0.0f;
    __syncthreads();
    if (tid == 0) {
      for (int e = 0; e < 16; ++e) {
        int aa = edge[e], bb = edge[16 + e];
        ws[WS_A + aa * 8 + bb] = 1.0f;
        ws[WS_A + bb * 8 + aa] = 1.0f;
      }
    }
    __syncthreads();
    if (tid < 64) ws[WS_PEN + tid] = 1000.0f * (1.0f - ws[WS_A + tid]);
  }
}

// ---------------- diversity (LDS design): dv[t][8] ----------------
__global__ void __launch_bounds__(256) k_diversity(
    const float* __restrict__ times, const float* __restrict__ d2,
    const float* __restrict__ d3, float* __restrict__ ws) {
  __shared__ float h1dT[128][64];
  __shared__ float h2dT[64][64];
  int tid = threadIdx.x;
  int s = tid & 63, w = tid >> 6;
  int t = blockIdx.x * 64 + s;
  float last = times[T_STEPS - 1];
  float st = (last > 0.0f) ? times[t] / last : 0.0f;
  int j0 = __builtin_amdgcn_readfirstlane(w * 32);
  #pragma unroll
  for (int jj = 0; jj < 32; ++jj) {
    int j = j0 + jj;
    h1dT[j][s] = fmaxf(fmaf(st, ws[WS_VDC + j], ws[WS_UDC + j]), 0.0f);
  }
  __syncthreads();
  j0 = __builtin_amdgcn_readfirstlane(w * 16);
  float acc[16];
  #pragma unroll
  for (int jj = 0; jj < 16; ++jj) acc[jj] = d2[j0 + jj];
  #pragma unroll 4
  for (int k = 0; k < 128; ++k) {
    float h = h1dT[k][s];
    #pragma unroll
    for (int jj = 0; jj < 16; ++jj)
      acc[jj] = fmaf(ws[WS_D2T + k * 64 + j0 + jj], h, acc[jj]);
  }
  #pragma unroll
  for (int jj = 0; jj < 16; ++jj) h2dT[j0 + jj][s] = fmaxf(acc[jj], 0.0f);
  __syncthreads();
  if (tid < 64) {
    float a8[8];
    #pragma unroll
    for (int z = 0; z < 8; ++z) a8[z] = d3[z];
    #pragma unroll 4
    for (int k = 0; k < 64; ++k) {
      float h = h2dT[k][s];
      #pragma unroll
      for (int z = 0; z < 8; ++z) a8[z] = fmaf(ws[WS_D3T + k * 8 + z], h, a8[z]);
    }
    #pragma unroll
    for (int z = 0; z < 8; ++z) ws[WS_DV + t * 8 + z] = tanhf(a8[z]);
  }
}

// ---------------- AB precompute v4: parallel endpoint evals ----------------
__global__ void __launch_bounds__(256) k_ab4(
    const float* __restrict__ times,
    const float* __restrict__ u_, const float* __restrict__ v_,
    const float* __restrict__ w1zt, const float* __restrict__ w2t,
    const float* __restrict__ w3t, const float* __restrict__ w4t,
    const float* __restrict__ b2, const float* __restrict__ b3,
    const float* __restrict__ b4,
    float* __restrict__ abt, int* __restrict__ crx,
    float* __restrict__ a4lr) {
  __shared__ float s_au[256], s_av[256];
  __shared__ float s_pa[128], s_pb[128];
  __shared__ unsigned long long s_bal[4];
  __shared__ float s_h2L[128], s_h2R[128];
  __shared__ float s_h3pL[4][64], s_h3pR[4][64];
  __shared__ float s_h3L[64], s_h3R[64];
  __shared__ int s_dirty, s_cnt;
  int blk = blockIdx.x;
  int c = blk >> 8, tile = blk & 255;
  int tid = threadIdx.x;
  float last = times[T_STEPS - 1];
  float stL = (last > 0.0f) ? times[tile * 64] / last : 0.0f;
  float stR = (last > 0.0f) ? times[tile * 64 + 63] / last : 0.0f;
  {
    float uk = u_[tid] + w1zt[c * 256 + tid];
    float vk = v_[tid];
    float valL = fmaf(stL, vk, uk);
    float valR = fmaf(stR, vk, uk);
    float mn = fminf(valL, valR);
    float mx = fmaxf(valL, valR);
    bool act = (mn > 0.0f);
    bool cross = (!act) && (mx > 0.0f);
    s_au[tid] = act ? uk : 0.0f;
    s_av[tid] = act ? vk : 0.0f;
    unsigned long long bal = __ballot(cross);
    if ((tid & 63) == 0) s_bal[tid >> 6] = bal;
  }
  if (tid == 0) s_dirty = 0;
  __syncthreads();
  if (tid == 0) {
    int cnt = 0;
    int list8[8];
    #pragma unroll
    for (int i = 0; i < 8; ++i) list8[i] = 0;
    #pragma unroll
    for (int w = 0; w < 4; ++w) {
      unsigned long long m = s_bal[w];
      while (m) {
        int bit = __ffsll(m) - 1;
        if (cnt < 8) list8[cnt] = w * 64 + bit;
        ++cnt;
        m &= (m - 1);
      }
    }
    crx[blk * 12] = cnt;
    s_cnt = cnt;
    #pragma unroll
    for (int i = 0; i < 8; ++i) crx[blk * 12 + 1 + i] = list8[i];
  }
  // masked matvec (A,B per j)
  {
    int j = tid & 127, half = tid >> 7;
    float A = 0.0f, B = 0.0f;
    const float* wrow = w2t + half * 128 * 128 + j;
    int kb = half * 128;
    #pragma unroll 4
    for (int kk = 0; kk < 128; ++kk) {
      float w = wrow[kk * 128];
      A = fmaf(s_au[kb + kk], w, A);
      B = fmaf(s_av[kb + kk], w, B);
    }
    if (half == 1) { s_pa[j] = A; s_pb[j] = B; }
    __syncthreads();
    if (half == 0) {
      float Af = A + s_pa[j] + b2[j];
      float Bf = B + s_pb[j];
      abt[(size_t)blk * 256 + j * 2]     = Af;
      abt[(size_t)blk * 256 + j * 2 + 1] = Bf;
      float preL = fmaf(stL, Bf, Af);
      float preR = fmaf(stR, Bf, Af);
      if ((preL > 0.0f) != (preR > 0.0f)) atomicOr(&s_dirty, 1);
      s_h2L[j] = fmaxf(preL, 0.0f);
      s_h2R[j] = fmaxf(preR, 0.0f);
    }
  }
  __syncthreads();
  // h3 endpoints, all 256 threads: thread = (i, j-quarter)
  {
    int i = tid & 63, jq = tid >> 6;
    float aL = (jq == 0) ? b3[i] : 0.0f;
    float aR = aL;
    int j0 = jq * 32;
    #pragma unroll 4
    for (int jj = 0; jj < 32; ++jj) {
      float w = w3t[(j0 + jj) * 64 + i];
      aL = fmaf(w, s_h2L[j0 + jj], aL);
      aR = fmaf(w, s_h2R[j0 + jj], aR);
    }
    s_h3pL[jq][i] = aL;
    s_h3pR[jq][i] = aR;
  }
  __syncthreads();
  if (tid < 64) {
    float aL = s_h3pL[0][tid] + s_h3pL[1][tid] + s_h3pL[2][tid] + s_h3pL[3][tid];
    float aR = s_h3pR[0][tid] + s_h3pR[1][tid] + s_h3pR[2][tid] + s_h3pR[3][tid];
    if ((aL > 0.0f) != (aR > 0.0f)) atomicOr(&s_dirty, 1);
    s_h3L[tid] = fmaxf(aL, 0.0f);
    s_h3R[tid] = fmaxf(aR, 0.0f);
  }
  __syncthreads();
  if (tid < 8) {
    float aL = b4[tid], aR = b4[tid];
    #pragma unroll 8
    for (int i = 0; i < 64; ++i) {
      float w = w4t[i * 8 + tid];
      aL = fmaf(w, s_h3L[i], aL);
      aR = fmaf(w, s_h3R[i], aR);
    }
    a4lr[blk * 16 + tid] = aL;
    a4lr[blk * 16 + 8 + tid] = aR;
  }
  if (tid == 0)
    crx[blk * 12 + 9] = (s_cnt == 0 && s_dirty == 0) ? 1 : 0;
}

// ---------------- fused MLP: single-c blocks, clean early-exit ----------------
__global__ void __launch_bounds__(256, 8) k_mlp(
    const float* __restrict__ times,
    const float* __restrict__ u_, const float* __restrict__ v_,
    const float* __restrict__ w1zt, const float* __restrict__ w2t,
    const float* __restrict__ abt, const int* __restrict__ crx,
    const float* __restrict__ a4lr,
    const float* __restrict__ w3t, const float* __restrict__ w4t,
    const float* __restrict__ b2, const float* __restrict__ b3,
    const float* __restrict__ b4,
    const float* __restrict__ dv, const float* __restrict__ gt,
    const float* __restrict__ pen, const float* __restrict__ tau,
    float* __restrict__ cons_out, unsigned char* __restrict__ nxt_out) {
  __shared__ float part[3][8][64];  // 6KB
  int tid = threadIdx.x;
  int lane = tid & 63;
  int iq = __builtin_amdgcn_readfirstlane(tid >> 6);  // 0..3
  int blk = blockIdx.x;          // c*256 + tgrp
  int c = blk >> 8, tgrp = blk & 255;
  int t = tgrp * 64 + lane;
  int abase = blk * 256;
  int cbase = blk * 12;
  int flag = crx[cbase + 9];

  if (flag) {
    // clean tile: a4 is affine in st -> lerp endpoints; wave 0 only, no barrier
    if (iq == 0) {
      float frac = (float)lane * (1.0f / 63.0f);
      float a4[8];
      #pragma unroll
      for (int z = 0; z < 8; ++z) {
        float L = a4lr[blk * 16 + z];
        float R = a4lr[blk * 16 + 8 + z];
        a4[z] = fmaf(frac, R - L, L);
      }
      float4 dv0 = *(const float4*)(dv + (size_t)t * 8);
      float4 dv1 = *(const float4*)(dv + (size_t)t * 8 + 4);
      float4 g0  = *(const float4*)(gt + (size_t)t * 8);
      float4 g1  = *(const float4*)(gt + (size_t)t * 8 + 4);
      float dvv[8] = {dv0.x, dv0.y, dv0.z, dv0.w, dv1.x, dv1.y, dv1.z, dv1.w};
      float gv[8]  = {g0.x, g0.y, g0.z, g0.w, g1.x, g1.y, g1.z, g1.w};
      float sgn = (tau[0] > 0.0f) ? 1.0f : -1.0f;
      float cons[8];
      float best = 0.0f; int bz = 0;
      #pragma unroll
      for (int z = 0; z < 8; ++z) {
        float lg = fmaf(0.2f, dvv[z], a4[z]) - pen[c * 8 + z];
        cons[z] = lg;
        float yv = (lg + gv[z]) * sgn;
        if (z == 0) { best = yv; bz = 0; }
        else if (yv > best) { best = yv; bz = z; }
      }
      float* co = cons_out + ((size_t)t * 8 + c) * 8;
      *(float4*)co = make_float4(cons[0], cons[1], cons[2], cons[3]);
      *(float4*)(co + 4) = make_float4(cons[4], cons[5], cons[6], cons[7]);
      nxt_out[t * 8 + c] = (unsigned char)bz;
    }
    return;
  }

  // dirty tile: exact path (R8 structure, one c)
  float last = times[T_STEPS - 1];
  float st = (last > 0.0f) ? times[t] / last : 0.0f;
  const float* w1c = w1zt + c * 256;
  int cnt = crx[cbase];

  float acc[16];
  #pragma unroll
  for (int i = 0; i < 16; ++i) acc[i] = b3[iq * 16 + i];
  const float* w3 = w3t + iq * 16;

  if (cnt == 0) {
    #pragma unroll 4
    for (int j = 0; j < 128; ++j) {
      float A = abt[abase + j * 2];
      float B = abt[abase + j * 2 + 1];
      float h2 = fmaxf(fmaf(st, B, A), 0.0f);
      #pragma unroll
      for (int i = 0; i < 16; ++i)
        acc[i] = fmaf(w3[j * 64 + i], h2, acc[i]);
    }
  } else if (cnt <= 8) {
    int kk[8];
    #pragma unroll
    for (int i = 0; i < 8; ++i) kk[i] = (i < cnt) ? crx[cbase + 1 + i] : 0;
    float hx[8];
    #pragma unroll
    for (int i = 0; i < 8; ++i)
      hx[i] = (i < cnt) ? fmaxf(fmaf(st, v_[kk[i]], u_[kk[i]] + w1c[kk[i]]), 0.0f) : 0.0f;
    #pragma unroll 2
    for (int j = 0; j < 128; ++j) {
      float A = abt[abase + j * 2];
      float B = abt[abase + j * 2 + 1];
      float h2p = fmaf(st, B, A);
      #pragma unroll
      for (int i = 0; i < 8; ++i)
        h2p = fmaf(hx[i], w2t[kk[i] * 128 + j], h2p);
      float h2 = fmaxf(h2p, 0.0f);
      #pragma unroll
      for (int i = 0; i < 16; ++i)
        acc[i] = fmaf(w3[j * 64 + i], h2, acc[i]);
    }
  } else {
    // exact brute-force (vanishingly rare)
    for (int j = 0; j < 128; ++j) {
      float h2p = b2[j];
      for (int k = 0; k < 256; ++k) {
        float h1 = fmaxf(fmaf(st, v_[k], u_[k] + w1c[k]), 0.0f);
        h2p = fmaf(w2t[k * 128 + j], h1, h2p);
      }
      float h2 = fmaxf(h2p, 0.0f);
      #pragma unroll
      for (int i = 0; i < 16; ++i)
        acc[i] = fmaf(w3[j * 64 + i], h2, acc[i]);
    }
  }

  // layer 4 partials over own 16 h3's
  float p[8];
  #pragma unroll
  for (int z = 0; z < 8; ++z) p[z] = (iq == 0) ? b4[z] : 0.0f;
  #pragma unroll 4
  for (int i = 0; i < 16; ++i) {
    float h3 = fmaxf(acc[i], 0.0f);
    #pragma unroll
    for (int z = 0; z < 8; ++z)
      p[z] = fmaf(w4t[(iq * 16 + i) * 8 + z], h3, p[z]);
  }
  if (iq > 0) {
    #pragma unroll
    for (int z = 0; z < 8; ++z) part[iq - 1][z][lane] = p[z];
  }
  __syncthreads();
  if (iq == 0) {
    float a4[8];
    #pragma unroll
    for (int z = 0; z < 8; ++z)
      a4[z] = p[z] + part[0][z][lane] + part[1][z][lane] + part[2][z][lane];
    float4 dv0 = *(const float4*)(dv + (size_t)t * 8);
    float4 dv1 = *(const float4*)(dv + (size_t)t * 8 + 4);
    float4 g0  = *(const float4*)(gt + (size_t)t * 8);
    float4 g1  = *(const float4*)(gt + (size_t)t * 8 + 4);
    float dvv[8] = {dv0.x, dv0.y, dv0.z, dv0.w, dv1.x, dv1.y, dv1.z, dv1.w};
    float gv[8]  = {g0.x, g0.y, g0.z, g0.w, g1.x, g1.y, g1.z, g1.w};
    float sgn = (tau[0] > 0.0f) ? 1.0f : -1.0f;
    float cons[8];
    float best = 0.0f; int bz = 0;
    #pragma unroll
    for (int z = 0; z < 8; ++z) {
      float lg = fmaf(0.2f, dvv[z], a4[z]) - pen[c * 8 + z];
      cons[z] = lg;
      float yv = (lg + gv[z]) * sgn;
      if (z == 0) { best = yv; bz = 0; }
      else if (yv > best) { best = yv; bz = z; }
    }
    float* co = cons_out + ((size_t)t * 8 + c) * 8;
    *(float4*)co = make_float4(cons[0], cons[1], cons[2], cons[3]);
    *(float4*)(co + 4) = make_float4(cons[4], cons[5], cons[6], cons[7]);
    nxt_out[t * 8 + c] = (unsigned char)bz;
  }
}

// ---------------- phase C: parallel prefix, 1024 threads x 16 steps ----------------
__global__ void __launch_bounds__(1024) k_phaseC(float* __restrict__ ws, float* __restrict__ d_out) {
  int tid = threadIdx.x;
  const unsigned char* nxt8 = (const unsigned char*)ws + WSB_NXT8;
  unsigned int* cur_arr = (unsigned int*)((char*)ws + WSB_CUR);
  const unsigned int IDENT = 0x00FAC688u;
  unsigned int f[16];
  int t0 = tid * 16;
  unsigned int F = IDENT;
  #pragma unroll
  for (int i = 0; i < 16; ++i) {
    uint2 b = *(const uint2*)(nxt8 + (size_t)(t0 + i) * 8);
    unsigned int fn = 0;
    #pragma unroll
    for (int q = 0; q < 4; ++q) fn |= ((b.x >> (8 * q)) & 7u) << (3 * q);
    #pragma unroll
    for (int q = 0; q < 4; ++q) fn |= ((b.y >> (8 * q)) & 7u) << (3 * (q + 4));
    f[i] = fn;
    F = fn_compose(fn, F);
  }
  __shared__ unsigned int sc[1024];
  sc[tid] = F;
  __syncthreads();
  #pragma unroll
  for (int d = 1; d < 1024; d <<= 1) {
    unsigned int v = sc[tid];
    unsigned int p = (tid >= d) ? sc[tid - d] : 0u;
    unsigned int nv = (tid >= d) ? fn_compose(v, p) : v;
    __syncthreads();
    sc[tid] = nv;
    __syncthreads();
  }
  unsigned int E = (tid == 0) ? IDENT : sc[tid - 1];
  unsigned int state = E & 7u;
  #pragma unroll
  for (int i = 0; i < 16; ++i) {
    int tt = t0 + i;
    cur_arr[tt] = state;
    unsigned int nx = (f[i] >> (3 * state)) & 7u;
    d_out[131072 + tt] = (float)nx;
    state = nx;
  }
}

// ---------------- gather ----------------
__global__ void k_gather(const float* __restrict__ ws, float* __restrict__ d_out) {
  int idx = blockIdx.x * 256 + threadIdx.x;
  const unsigned int* cur_arr = (const unsigned int*)((const char*)ws + WSB_CUR);
  int t = idx >> 3, z = idx & 7;
  unsigned int cur = cur_arr[t];
  d_out[idx] = ws[WS_CONS + (t * 8 + (int)cur) * 8 + z];
}

extern "C" void kernel_launch(void* const* d_in, const int* in_sizes, int n_in,
                              void* d_out, int out_size, void* d_ws, size_t ws_size,
                              hipStream_t stream) {
  const float* pa    = (const float*)d_in[0];
  const float* times = (const float*)d_in[1];
  const float* gum   = (const float*)d_in[2];
  const int*   edge  = (const int*)d_in[3];
  const float* W1  = (const float*)d_in[4];
  const float* b1  = (const float*)d_in[5];
  const float* W2  = (const float*)d_in[6];
  const float* b2  = (const float*)d_in[7];
  const float* W3  = (const float*)d_in[8];
  const float* b3  = (const float*)d_in[9];
  const float* W4  = (const float*)d_in[10];
  const float* b4  = (const float*)d_in[11];
  const float* D1  = (const float*)d_in[12];
  const float* d1v = (const float*)d_in[13];
  const float* D2  = (const float*)d_in[14];
  const float* d2v = (const float*)d_in[15];
  const float* D3  = (const float*)d_in[16];
  const float* d3v = (const float*)d_in[17];
  const float* tau = (const float*)d_in[18];
  float* ws = (float*)d_ws;
  float* out = (float*)d_out;
  int* crx = (int*)((char*)d_ws + WSB_CRX);

  k_prepAll<<<705, 256, 0, stream>>>(pa, gum, edge, W1, b1, W2, W3, W4,
                                     D1, d1v, D2, D3, ws);
  k_diversity<<<256, 256, 0, stream>>>(times, d2v, d3v, ws);
  k_ab4<<<2048, 256, 0, stream>>>(times, ws + WS_U, ws + WS_V, ws + WS_W1ZT,
                                  ws + WS_W2T, ws + WS_W3T, ws + WS_W4T,
                                  b2, b3, b4, ws + WS_ABT, crx, ws + WS_A4LR);
  k_mlp<<<2048, 256, 0, stream>>>(times, ws + WS_U, ws + WS_V, ws + WS_W1ZT,
                                  ws + WS_W2T, ws + WS_ABT, crx, ws + WS_A4LR,
                                  ws + WS_W3T, ws + WS_W4T, b2, b3, b4,
                                  ws + WS_DV, ws + WS_G, ws + WS_PEN, tau,
                                  ws + WS_CONS, (unsigned char*)ws + WSB_NXT8);
  k_phaseC<<<1, 1024, 0, stream>>>(ws, out);
  k_gather<<<512, 256, 0, stream>>>(ws, out);
}